// Round 2
// baseline (1858.716 us; speedup 1.0000x reference)
//
#include <hip/hip_runtime.h>

// LIF scan: B=16, S=256, H=128, N=64. T = S*H = 32768 sequential steps per
// (b,n) chain; 1024 chains. Bit-exactness with the fp32 sequential reference
// required -> add chain cannot be reassociated. Chain form (proven bit-exact):
//     s' = prev ? x : fl(s + x);  prev' = s' > th
//
// R9: replace the sequential pass1 (378 us, 27.7 cyc/step; every staging
// variant R6-R8 lands at 24-28 cyc/step vs the ~8-10 cyc dep-chain floor)
// with SPECULATIVE COALESCENCE. Key property: the recurrence forgets its
// history at every spike (post-spike state = x_next exactly). Two runs of
// the same row that spike on the same step are bit-identical afterwards.
//  K1z (parallel, 4096 waves): z-run every row from the canonical fresh
//    state (prev=true); record 63-bit spike mask + bit63=exit-spike + exit
//    state z_end. No output writes. ~4 us.
//  K2 (sequential, 16 waves): walk rows with true (s,prev). prev_in=true
//    -> row IS the z-run, adopt z_end, 0 chain steps (~30% of rows).
//    Else re-run until first simultaneous spike with the z-mask (E[max over
//    live lanes] ~12 steps), adopt z_end. No coalescence by step 62 ->
//    full 128-step re-run (correct for any data). Emits old checkpoints.
//  K3: R8 pass2 unchanged (replay+dense write, harness-proven bit-exact).

namespace {
constexpr int kB = 16;
constexpr int kS = 256;
constexpr int kH = 128;
constexpr int kN = 64;
constexpr int kT = kS * kH;                 // 32768
constexpr long kPerB = (long)kS * kN * kH;  // 2,097,152 per batch per tensor
// new ws layout: zend | zmask | ckpt_s | ckpt_m
constexpr size_t kWsZ = (size_t)kB * kS * kN * sizeof(float);                // 1 MB
constexpr size_t kWsMk = (size_t)kB * kS * kN * sizeof(unsigned long long);  // 2 MB
constexpr size_t kWsS = (size_t)kB * kS * kN * sizeof(float);                // 1 MB
constexpr size_t kWsM = (size_t)kB * kS * sizeof(unsigned long long);        // 32 KB
}

typedef float v4f __attribute__((ext_vector_type(4)));
typedef unsigned long long u64;

// Opaque VGPR zero: defeats uniform-scalarization so wave-uniform-looking
// loads use the vector path (vmcnt, in-order) instead of SMEM s_loads
// (lgkmcnt, unordered -> full drains). Proven effective in R6.
__device__ __forceinline__ int opaque_vgpr_zero() {
  int z;
  asm volatile("v_mov_b32 %0, 0" : "=v"(z));
  return z;
}

// ---------------------------------------------------------------------------
// K1z: z-run every (b,row) from the fresh state (prev=true -> step 0 gives
// s = x_0 exactly). Store per-lane: spike mask bits 0..62 = spikes at steps
// 0..62, bit 63 = spike at step 127 (row-exit prev); z_end = exit state.
// ---------------------------------------------------------------------------
__global__ __launch_bounds__(64, 2) void lif_zrun_kernel(
    const float* __restrict__ x, const float* __restrict__ thresh,
    float* __restrict__ zend, u64* __restrict__ zmask) {
  const int wid = blockIdx.x;
  const int b = wid >> 8;
  const int srow = wid & 255;
  const int lane = threadIdx.x;

  const v4f* __restrict__ xr4 =
      (const v4f*)(x + (long)b * kT + srow * kH) + opaque_vgpr_zero();
  v4f xb[32];
#pragma unroll
  for (int i = 0; i < 32; ++i) xb[i] = xr4[i];  // 32 loads in flight

  const float th = thresh[lane];
  float s = 0.0f;
  bool prev = true;  // fresh start: step 0 takes s = x_0
  u64 m = 0;

#pragma unroll
  for (int h = 0; h < kH; ++h) {
    const float xt = xb[h >> 2][h & 3];
    const float u = s + xt;
    s = prev ? xt : u;
    prev = s > th;
    if (h < 63) m |= (u64)prev << h;
    if (h == 127) m |= (u64)prev << 63;
  }
  zend[((long)b * kS + srow) * kN + lane] = s;
  zmask[((long)b * kS + srow) * kN + lane] = m;
}

// ---------------------------------------------------------------------------
// K2: sequential stitch. block = batch, lane = neuron. Carries true (s,prev)
// across rows; per row writes the checkpoint (entering state + ballot(prev))
// then advances to the row-exit state via coalescence with the z-run.
// ---------------------------------------------------------------------------
__global__ __launch_bounds__(64, 1) void lif_stitch_kernel(
    const float* __restrict__ x, const float* __restrict__ thresh,
    const float* __restrict__ acc0, const float* __restrict__ zend,
    const u64* __restrict__ zmask, float* __restrict__ ckpt_s,
    u64* __restrict__ ckpt_m) {
  const int b = blockIdx.x;
  const int lane = threadIdx.x;
  const float th = thresh[lane];

  float s = acc0[b * kN + lane];
  bool prev = false;

  const float* __restrict__ xb = x + (long)b * kT + opaque_vgpr_zero();
  const u64* __restrict__ mrow = zmask + (long)b * kS * kN + lane;
  const float* __restrict__ zrow = zend + (long)b * kS * kN + lane;
  float* __restrict__ cs = ckpt_s + (long)b * kS * kN + lane;
  u64* __restrict__ cm = ckpt_m + (long)b * kS;

  // prefetch row 0 (mask, z_end, first 32 x values)
  u64 nm = mrow[0];
  float nze = zrow[0];
  const v4f* __restrict__ xr0 = (const v4f*)xb;
  v4f nq0 = xr0[0], nq1 = xr0[1], nq2 = xr0[2], nq3 = xr0[3];
  v4f nq4 = xr0[4], nq5 = xr0[5], nq6 = xr0[6], nq7 = xr0[7];

  for (int r = 0; r < kS; ++r) {
    const u64 zm = nm;
    const float ze = nze;
    const v4f q0 = nq0, q1 = nq1, q2 = nq2, q3 = nq3;
    const v4f q4 = nq4, q5 = nq5, q6 = nq6, q7 = nq7;

    // issue next-row prefetch (consumed next iteration; hides latency)
    const int rn = (r + 1 < kS) ? r + 1 : r;
    nm = mrow[(long)rn * kN];
    nze = zrow[(long)rn * kN];
    const v4f* __restrict__ xrn = (const v4f*)(xb + (long)rn * kH);
    nq0 = xrn[0]; nq1 = xrn[1]; nq2 = xrn[2]; nq3 = xrn[3];
    nq4 = xrn[4]; nq5 = xrn[5]; nq6 = xrn[6]; nq7 = xrn[7];

    // checkpoint: entering state
    cs[(long)r * kN] = s;
    {
      const u64 cmask = __ballot(prev);
      if (lane == 0) cm[r] = cmask;
    }

    bool live = !prev;  // prev_in=true lanes: row == z-run, adopt z directly
    float srun = s;
    bool prun = prev;

#define LIF_STEP(hconst, xt)                                                 \
  {                                                                          \
    const float u_ = srun + (xt);                                            \
    srun = prun ? (xt) : u_;                                                 \
    prun = srun > th;                                                        \
    if ((hconst) < 63) live = live && !(prun && ((zm >> (hconst)) & 1ull));  \
  }

    if (__ballot(live) != 0) {
      bool done = false;
#define LIF_GROUP(g, qv)              \
  if (!done) {                        \
    LIF_STEP(4 * (g) + 0, (qv)[0]);   \
    LIF_STEP(4 * (g) + 1, (qv)[1]);   \
    LIF_STEP(4 * (g) + 2, (qv)[2]);   \
    LIF_STEP(4 * (g) + 3, (qv)[3]);   \
    done = (__ballot(live) == 0);     \
  }
      LIF_GROUP(0, q0)
      LIF_GROUP(1, q1)
      LIF_GROUP(2, q2)
      LIF_GROUP(3, q3)
      LIF_GROUP(4, q4)
      LIF_GROUP(5, q5)
      LIF_GROUP(6, q6)
      LIF_GROUP(7, q7)
#undef LIF_GROUP
      if (!done) {
        // rare: some lane uncoalesced past step 31 -> demand-load groups.
        const v4f* __restrict__ xrc = (const v4f*)(xb + (long)r * kH);
        for (int g = 8; g < 32; ++g) {
          const v4f dv = xrc[g];
#pragma unroll
          for (int j = 0; j < 4; ++j) {
            const int h = 4 * g + j;
            const float xt = dv[j];
            const float u_ = srun + xt;
            srun = prun ? xt : u_;
            prun = srun > th;
            if (h < 63) live = live && !(prun && ((zm >> h) & 1ull));
          }
          if (__ballot(live) == 0) break;
        }
      }
    }
#undef LIF_STEP
    // live here == ran all 128 steps without coalescing (full re-run):
    // srun/prun are the true exit state. Otherwise the z-run is authoritative
    // from the coalescence step on -> exit state = z_end, exit prev = bit 63.
    s = live ? srun : ze;
    prev = live ? prun : (bool)((zm >> 63) & 1ull);
  }
}

// ---------------------------------------------------------------------------
// K3: replay + dense coalesced write (byte-identical to R8 pass2, which
// passed with absmax = 0). One wave per (b,row); lane = n.
// ---------------------------------------------------------------------------
__global__ __launch_bounds__(64, 2) void lif_pass2_kernel(
    const float* __restrict__ x, const float* __restrict__ thresh,
    const float* __restrict__ ckpt_s, const u64* __restrict__ ckpt_m,
    float* __restrict__ out) {
  const int wid = blockIdx.x;
  const int b = wid >> 8;
  const int srow = wid & 255;
  const int lane = threadIdx.x;

  __shared__ float ov[kH / 2][kN + 1];  // 16.6 KB

  const v4f* __restrict__ xr4 =
      (const v4f*)(x + (long)b * kT + srow * kH) + opaque_vgpr_zero();

  v4f xb[32];
#pragma unroll
  for (int i = 0; i < 32; ++i) xb[i] = xr4[i];  // 32 loads in flight

  const float th = thresh[lane];
  float s = ckpt_s[((long)b * kS + srow) * kN + lane];
  bool prev = (ckpt_m[b * kS + srow] >> lane) & 1ULL;

  float* __restrict__ obase = out + (long)b * kPerB + (long)srow * (kN * kH);
  float* __restrict__ sbase = obase + (long)kB * kPerB;

#pragma unroll
  for (int half = 0; half < 2; ++half) {
#pragma unroll
    for (int hh = 0; hh < kH / 2; ++hh) {
      const int h = half * (kH / 2) + hh;
      const float xt = xb[h >> 2][h & 3];
      const float u = s + xt;
      s = prev ? xt : u;  // bit-identical replay
      prev = s > th;
      ov[hh][lane] = prev ? s : 0.0f;
    }
    const int q = lane & 15;
    const int nsub = lane >> 4;
    const int h0 = half * (kH / 2) + q * 4;
#pragma unroll
    for (int i = 0; i < 16; ++i) {
      const int n = i * 4 + nsub;
      v4f o, sp;
#pragma unroll
      for (int j = 0; j < 4; ++j) {
        const float v = ov[q * 4 + j][n];
        o[j] = v;
        sp[j] = v > 0.0f ? 1.0f : 0.0f;
      }
      *(v4f*)(obase + (long)n * kH + h0) = o;
      *(v4f*)(sbase + (long)n * kH + h0) = sp;
    }
  }
}

// ---------------------------------------------------------------------------
// Fallback A (ws in [1.03MB, 4.03MB)): R8 sequential pass1 + pass2.
// ---------------------------------------------------------------------------
__global__ __launch_bounds__(64, 1) void lif_pass1_kernel(
    const float* __restrict__ x, const float* __restrict__ thresh,
    const float* __restrict__ acc0, float* __restrict__ ckpt_s,
    u64* __restrict__ ckpt_m) {
  const int b = blockIdx.x;
  const int lane = threadIdx.x;
  const float th = thresh[lane];

  __shared__ v4f xs[2048];  // 32 KB: one quarter of this batch's x stream

  const v4f* __restrict__ xg =
      (const v4f*)(x + (long)b * kT) + opaque_vgpr_zero();

  float s = acc0[b * kN + lane];
  bool prev = false;

  float* __restrict__ cs = ckpt_s + (long)b * kS * kN + lane;
  u64* __restrict__ cm = ckpt_m + (long)b * kS;

  for (int q = 0; q < 4; ++q) {
    {
      const v4f* __restrict__ src = xg + (long)q * 2048 + lane;
      v4f tmp[32];
#pragma unroll
      for (int i = 0; i < 32; ++i) tmp[i] = src[i * 64];
#pragma unroll
      for (int i = 0; i < 32; ++i) xs[i * 64 + lane] = tmp[i];
    }
    for (int jrow = 0; jrow < 64; ++jrow) {
      const int r = q * 64 + jrow;
      cs[(long)r * kN] = s;
      {
        const u64 m = __ballot(prev);
        if (lane == 0) cm[r] = m;
      }
      const v4f* __restrict__ xr = &xs[jrow * 32];
#pragma unroll
      for (int k = 0; k < 32; ++k) {
        const v4f xv = xr[k];
#pragma unroll
        for (int j = 0; j < 4; ++j) {
          const float xt = xv[j];
          const float u = s + xt;
          s = prev ? xt : u;
          prev = s > th;
        }
      }
    }
  }
}

// ---------------------------------------------------------------------------
// Fallback B (tiny ws): R4's passing fused kernel (unchanged).
// ---------------------------------------------------------------------------
__global__ __launch_bounds__(128) void lif_fused_kernel(
    const float* __restrict__ x, const float* __restrict__ thresh,
    const float* __restrict__ acc0, float* __restrict__ out) {
  const int bid = blockIdx.x;
  const int b = bid >> 2;
  const int ng = bid & 3;
  const int tid = threadIdx.x;
  const int wave = tid >> 6;
  const int lane = tid & 63;
  __shared__ float buf[2][kH][64];
  const float* __restrict__ xb = x + (long)b * kT;
  float* __restrict__ outs_g = out + (long)b * kPerB + (long)(ng * 16) * kH;
  float* __restrict__ spks_g = outs_g + (long)kB * kPerB;
  if (wave == 0) {
    const int n = lane & 15;
    const float th = thresh[ng * 16 + n];
    float s = acc0[b * kN + ng * 16 + n];
    bool prev = false;
    for (int r = 0; r < kS + 1; ++r) {
      if (r < kS) {
        float* __restrict__ bk = &buf[r & 1][0][lane];
        const float* __restrict__ xr = xb + r * kH;
#pragma unroll
        for (int k = 0; k < kH; ++k) {
          const float xt = xr[k];
          const float u = s + xt;
          s = prev ? xt : u;
          prev = s > th;
          bk[k * 64] = s;
        }
      }
      __syncthreads();
    }
  } else {
    const int n = lane >> 2;
    const int hg = lane & 3;
    const float th = thresh[ng * 16 + n];
    for (int r = 0; r < kS + 1; ++r) {
      if (r > 0) {
        const int rr = r - 1;
        const float(*bk)[64] = buf[rr & 1];
        float* __restrict__ orow = outs_g + (long)rr * (kN * kH) + n * kH;
        float* __restrict__ srow = spks_g + (long)rr * (kN * kH) + n * kH;
#pragma unroll
        for (int i = 0; i < 8; ++i) {
          const int hh = hg * 4 + i * 16;
          v4f ovv, sv;
#pragma unroll
          for (int j = 0; j < 4; ++j) {
            const float v = bk[hh + j][n];
            const bool sp = v > th;
            ovv[j] = sp ? v : 0.0f;
            sv[j] = sp ? 1.0f : 0.0f;
          }
          *(v4f*)(orow + hh) = ovv;
          *(v4f*)(srow + hh) = sv;
        }
      }
      __syncthreads();
    }
  }
}

// ---------------------------------------------------------------------------
extern "C" void kernel_launch(void* const* d_in, const int* in_sizes, int n_in,
                              void* d_out, int out_size, void* d_ws, size_t ws_size,
                              hipStream_t stream) {
  const float* inputs = (const float*)d_in[0];    // [B,S,H] fp32
  const float* threshes = (const float*)d_in[1];  // [N] fp32
  const float* acc0 = (const float*)d_in[2];      // [B,N] fp32
  float* out = (float*)d_out;

  if (ws_size >= kWsZ + kWsMk + kWsS + kWsM) {
    float* zendp = (float*)d_ws;
    u64* zmaskp = (u64*)((char*)d_ws + kWsZ);
    float* ckpt_s = (float*)((char*)d_ws + kWsZ + kWsMk);
    u64* ckpt_m = (u64*)((char*)d_ws + kWsZ + kWsMk + kWsS);
    lif_zrun_kernel<<<kB * kS, kN, 0, stream>>>(inputs, threshes, zendp,
                                                zmaskp);
    lif_stitch_kernel<<<kB, kN, 0, stream>>>(inputs, threshes, acc0, zendp,
                                             zmaskp, ckpt_s, ckpt_m);
    lif_pass2_kernel<<<kB * kS, kN, 0, stream>>>(inputs, threshes, ckpt_s,
                                                 ckpt_m, out);
  } else if (ws_size >= kWsS + kWsM) {
    float* ckpt_s = (float*)d_ws;
    u64* ckpt_m = (u64*)((char*)d_ws + kWsS);
    lif_pass1_kernel<<<kB, kN, 0, stream>>>(inputs, threshes, acc0, ckpt_s,
                                            ckpt_m);
    lif_pass2_kernel<<<kB * kS, kN, 0, stream>>>(inputs, threshes, ckpt_s,
                                                 ckpt_m, out);
  } else {
    lif_fused_kernel<<<kB * 4, 128, 0, stream>>>(inputs, threshes, acc0, out);
  }
}

// Round 3
// 777.431 us; speedup vs baseline: 2.3908x; 2.3908x over previous
//
#include <hip/hip_runtime.h>

// LIF scan: B=16, S=256, H=128, N=64. T = S*H = 32768 sequential steps per
// (b,n) chain; 1024 chains. Bit-exactness with the fp32 sequential reference
// required -> add chain cannot be reassociated. Chain form (proven bit-exact):
//     s' = prev ? x : fl(s + x);  prev' = s' > th
//
// R10: keep R9's speculative coalescence (math proven: absmax=0.0), fix the
// stitch's memory system. R9 stitch = 1613us (15k cyc/row, VALUBusy 0.5%):
// 16 waves total, every per-row load a full-latency round trip, and K1z's
// results live in OTHER XCDs' L2 (cross-XCD miss ~500-900cyc, serialized).
//  K1z: z-run every row from the fresh state; emit PACKED uint2 per lane:
//    .x bits0..30 = spike at steps 0..30, bit31 = exit prev (step 127);
//    .y = bitcast(exit state).
//  K2 stitch: one block per batch, 2 waves. Wave1 = producer: streams x +
//    zpack into double-buffered LDS (64KB/quarter, 128KB total). Wave0 =
//    consumer: per row reads mask+x from LDS only; re-runs until first
//    simultaneous spike with the z-run (E[max over live lanes] ~28 steps,
//    window 31), adopts z exit; else blind full re-run (pure VALU from
//    LDS). Zero global loads on the critical path.
//  K3 pass2: BYTE-IDENTICAL to R8/R9 (proven absmax=0.0) -> becomes the
//    top dispatch; next round gets its real counters.

namespace {
constexpr int kB = 16;
constexpr int kS = 256;
constexpr int kH = 128;
constexpr int kN = 64;
constexpr int kT = kS * kH;                 // 32768
constexpr long kPerB = (long)kS * kN * kH;  // 2,097,152 per batch per tensor
// ws layout: zpack | ckpt_s | ckpt_m
constexpr size_t kWsZp = (size_t)kB * kS * kN * 8;                     // 2 MB
constexpr size_t kWsS = (size_t)kB * kS * kN * sizeof(float);          // 1 MB
constexpr size_t kWsM = (size_t)kB * kS * sizeof(unsigned long long);  // 32 KB
}

typedef float v4f __attribute__((ext_vector_type(4)));
typedef unsigned long long u64;

// Opaque VGPR zero: defeats uniform-scalarization so wave-uniform-looking
// loads use the vector path (vmcnt, in-order) instead of SMEM s_loads
// (lgkmcnt, unordered -> full drains). Proven effective in R6.
__device__ __forceinline__ int opaque_vgpr_zero() {
  int z;
  asm volatile("v_mov_b32 %0, 0" : "=v"(z));
  return z;
}

// ---------------------------------------------------------------------------
// K1z: z-run every (b,row) from the fresh state (prev=true -> step 0 gives
// s = x_0 exactly). Packed result: .x bits0..30 spike@step0..30, bit31 =
// exit prev; .y = bitcast(exit state).
// ---------------------------------------------------------------------------
__global__ __launch_bounds__(64, 2) void lif_zrun_kernel(
    const float* __restrict__ x, const float* __restrict__ thresh,
    uint2* __restrict__ zpack) {
  const int wid = blockIdx.x;
  const int b = wid >> 8;
  const int srow = wid & 255;
  const int lane = threadIdx.x;

  const v4f* __restrict__ xr4 =
      (const v4f*)(x + (long)b * kT + srow * kH) + opaque_vgpr_zero();
  v4f xb[32];
#pragma unroll
  for (int i = 0; i < 32; ++i) xb[i] = xr4[i];  // 32 loads in flight

  const float th = thresh[lane];
  float s = 0.0f;
  bool prev = true;  // fresh start: step 0 takes s = x_0
  unsigned m = 0;

#pragma unroll
  for (int h = 0; h < kH; ++h) {
    const float xt = xb[h >> 2][h & 3];
    const float u = s + xt;
    s = prev ? xt : u;
    prev = s > th;
    if (h < 31) m |= (unsigned)prev << h;
    if (h == 127) m |= (unsigned)prev << 31;
  }
  uint2 zp;
  zp.x = m;
  zp.y = __float_as_uint(s);
  zpack[((long)b * kS + srow) * kN + lane] = zp;
}

// ---------------------------------------------------------------------------
// K2: stitch. One block per batch, 128 threads = {consumer wave, producer
// wave}. Producer double-buffers 64-row quarters of x (32KB) + zpack (32KB)
// into LDS; consumer carries true (s,prev) across 256 rows touching LDS
// only. Emits the same checkpoints as the old sequential pass1.
// ---------------------------------------------------------------------------
__global__ __launch_bounds__(128, 1) void lif_stitch_kernel(
    const float* __restrict__ x, const float* __restrict__ thresh,
    const float* __restrict__ acc0, const uint2* __restrict__ zpack,
    float* __restrict__ ckpt_s, u64* __restrict__ ckpt_m) {
  const int b = blockIdx.x;
  const int tid = threadIdx.x;
  const int wave = tid >> 6;
  const int lane = tid & 63;

  __shared__ v4f xsb[2][2048];  // 2 x 32KB: x quarter
  __shared__ v4f zsb[2][2048];  // 2 x 32KB: zpack quarter (type-punned uint2)

  if (wave == 1) {
    // ---- producer: stream quarters into LDS (global -> reg -> ds_write)
    const v4f* __restrict__ xg =
        (const v4f*)(x + (long)b * kT) + opaque_vgpr_zero();
    const v4f* __restrict__ zg =
        (const v4f*)(zpack + (long)b * kS * kN) + opaque_vgpr_zero();

    // stage quarter 0 into buf 0
#pragma unroll 1
    for (int q = -1; q < 3; ++q) {
      const int qq = q + 1;
      const int buf = qq & 1;
      const v4f* __restrict__ xsrc = xg + (long)qq * 2048;
      const v4f* __restrict__ zsrc = zg + (long)qq * 2048;
#pragma unroll 1
      for (int c = 0; c < 2; ++c) {
        v4f tx[16], tz[16];
#pragma unroll
        for (int i = 0; i < 16; ++i) tx[i] = xsrc[(c * 16 + i) * 64 + lane];
#pragma unroll
        for (int i = 0; i < 16; ++i) tz[i] = zsrc[(c * 16 + i) * 64 + lane];
#pragma unroll
        for (int i = 0; i < 16; ++i) xsb[buf][(c * 16 + i) * 64 + lane] = tx[i];
#pragma unroll
        for (int i = 0; i < 16; ++i) zsb[buf][(c * 16 + i) * 64 + lane] = tz[i];
      }
      __syncthreads();  // quarter qq ready / consumer done with buf (for q>=0)
    }
    __syncthreads();  // match consumer's final barrier
  } else {
    // ---- consumer: the true chain, LDS-only on the critical path
    const float th = thresh[lane];
    float s = acc0[b * kN + lane];
    bool prev = false;

    float* __restrict__ cs = ckpt_s + (long)b * kS * kN + lane;
    u64* __restrict__ cm = ckpt_m + (long)b * kS;

    __syncthreads();  // quarter 0 staged
    for (int q = 0; q < 4; ++q) {
      const v4f* __restrict__ xq = xsb[q & 1];
      const uint2* __restrict__ zq = (const uint2*)zsb[q & 1];
      for (int jr = 0; jr < 64; ++jr) {
        const int r = q * 64 + jr;
        const uint2 zp = zq[jr * 64 + lane];  // ds_read_b64, 2-way (free)

        cs[(long)r * kN] = s;  // checkpoint entering state
        {
          const u64 cmask = __ballot(prev);
          if (lane == 0) cm[r] = cmask;
        }

        const unsigned zm = zp.x;
        bool live = !prev;  // prev_in=true: row IS the z-run, adopt directly
        float srun = s;
        bool prun = prev;

        if (__ballot(live) != 0) {
          const v4f* __restrict__ xr = &xq[jr * 32];
          v4f qv[8];
#pragma unroll
          for (int g = 0; g < 8; ++g) qv[g] = xr[g];  // 8 reads in flight

#define LIF_STEPC(hconst, xt)                                               \
  {                                                                         \
    const float u_ = srun + (xt);                                           \
    srun = prun ? (xt) : u_;                                                \
    prun = srun > th;                                                       \
    if ((hconst) < 31) live = live && !(prun && ((zm >> (hconst)) & 1u));   \
  }
          bool done = false;
#define LIF_GROUP(g)                 \
  if (!done) {                       \
    LIF_STEPC(4 * (g) + 0, qv[g][0]) \
    LIF_STEPC(4 * (g) + 1, qv[g][1]) \
    LIF_STEPC(4 * (g) + 2, qv[g][2]) \
    LIF_STEPC(4 * (g) + 3, qv[g][3]) \
    done = (__ballot(live) == 0);    \
  }
          LIF_GROUP(0)
          LIF_GROUP(1)
          LIF_GROUP(2)
          LIF_GROUP(3)
          LIF_GROUP(4)
          LIF_GROUP(5)
          LIF_GROUP(6)
          LIF_GROUP(7)
#undef LIF_GROUP
          if (!done) {
            // rare: some lane uncoalesced by step 31 -> blind full re-run,
            // pure VALU from LDS (correct for any data).
#pragma unroll
            for (int g = 8; g < 32; ++g) {
              const v4f dv = xr[g];
#pragma unroll
              for (int j = 0; j < 4; ++j) {
                const float xt = dv[j];
                const float u_ = srun + xt;
                srun = prun ? xt : u_;
                prun = srun > th;
              }
            }
          }
#undef LIF_STEPC
        }
        // live == ran all 128 steps (srun/prun are truth); else z-run is
        // authoritative from the coalescence step on.
        s = live ? srun : __uint_as_float(zp.y);
        prev = live ? prun : (bool)(zm >> 31);
      }
      __syncthreads();  // hand buffer back to producer / next quarter ready
    }
  }
}

// ---------------------------------------------------------------------------
// K3: replay + dense coalesced write (byte-identical to R8/R9 pass2, proven
// absmax = 0). One wave per (b,row); lane = n.
// ---------------------------------------------------------------------------
__global__ __launch_bounds__(64, 2) void lif_pass2_kernel(
    const float* __restrict__ x, const float* __restrict__ thresh,
    const float* __restrict__ ckpt_s, const u64* __restrict__ ckpt_m,
    float* __restrict__ out) {
  const int wid = blockIdx.x;
  const int b = wid >> 8;
  const int srow = wid & 255;
  const int lane = threadIdx.x;

  __shared__ float ov[kH / 2][kN + 1];  // 16.6 KB

  const v4f* __restrict__ xr4 =
      (const v4f*)(x + (long)b * kT + srow * kH) + opaque_vgpr_zero();

  v4f xb[32];
#pragma unroll
  for (int i = 0; i < 32; ++i) xb[i] = xr4[i];  // 32 loads in flight

  const float th = thresh[lane];
  float s = ckpt_s[((long)b * kS + srow) * kN + lane];
  bool prev = (ckpt_m[b * kS + srow] >> lane) & 1ULL;

  float* __restrict__ obase = out + (long)b * kPerB + (long)srow * (kN * kH);
  float* __restrict__ sbase = obase + (long)kB * kPerB;

#pragma unroll
  for (int half = 0; half < 2; ++half) {
#pragma unroll
    for (int hh = 0; hh < kH / 2; ++hh) {
      const int h = half * (kH / 2) + hh;
      const float xt = xb[h >> 2][h & 3];
      const float u = s + xt;
      s = prev ? xt : u;  // bit-identical replay
      prev = s > th;
      ov[hh][lane] = prev ? s : 0.0f;
    }
    const int q = lane & 15;
    const int nsub = lane >> 4;
    const int h0 = half * (kH / 2) + q * 4;
#pragma unroll
    for (int i = 0; i < 16; ++i) {
      const int n = i * 4 + nsub;
      v4f o, sp;
#pragma unroll
      for (int j = 0; j < 4; ++j) {
        const float v = ov[q * 4 + j][n];
        o[j] = v;
        sp[j] = v > 0.0f ? 1.0f : 0.0f;
      }
      *(v4f*)(obase + (long)n * kH + h0) = o;
      *(v4f*)(sbase + (long)n * kH + h0) = sp;
    }
  }
}

// ---------------------------------------------------------------------------
// Fallback A (ws in [1.03MB, 3.03MB)): R8 sequential pass1 + pass2.
// ---------------------------------------------------------------------------
__global__ __launch_bounds__(64, 1) void lif_pass1_kernel(
    const float* __restrict__ x, const float* __restrict__ thresh,
    const float* __restrict__ acc0, float* __restrict__ ckpt_s,
    u64* __restrict__ ckpt_m) {
  const int b = blockIdx.x;
  const int lane = threadIdx.x;
  const float th = thresh[lane];

  __shared__ v4f xs[2048];  // 32 KB: one quarter of this batch's x stream

  const v4f* __restrict__ xg =
      (const v4f*)(x + (long)b * kT) + opaque_vgpr_zero();

  float s = acc0[b * kN + lane];
  bool prev = false;

  float* __restrict__ cs = ckpt_s + (long)b * kS * kN + lane;
  u64* __restrict__ cm = ckpt_m + (long)b * kS;

  for (int q = 0; q < 4; ++q) {
    {
      const v4f* __restrict__ src = xg + (long)q * 2048 + lane;
      v4f tmp[32];
#pragma unroll
      for (int i = 0; i < 32; ++i) tmp[i] = src[i * 64];
#pragma unroll
      for (int i = 0; i < 32; ++i) xs[i * 64 + lane] = tmp[i];
    }
    for (int jrow = 0; jrow < 64; ++jrow) {
      const int r = q * 64 + jrow;
      cs[(long)r * kN] = s;
      {
        const u64 m = __ballot(prev);
        if (lane == 0) cm[r] = m;
      }
      const v4f* __restrict__ xr = &xs[jrow * 32];
#pragma unroll
      for (int k = 0; k < 32; ++k) {
        const v4f xv = xr[k];
#pragma unroll
        for (int j = 0; j < 4; ++j) {
          const float xt = xv[j];
          const float u = s + xt;
          s = prev ? xt : u;
          prev = s > th;
        }
      }
    }
  }
}

// ---------------------------------------------------------------------------
// Fallback B (tiny ws): R4's passing fused kernel (unchanged).
// ---------------------------------------------------------------------------
__global__ __launch_bounds__(128) void lif_fused_kernel(
    const float* __restrict__ x, const float* __restrict__ thresh,
    const float* __restrict__ acc0, float* __restrict__ out) {
  const int bid = blockIdx.x;
  const int b = bid >> 2;
  const int ng = bid & 3;
  const int tid = threadIdx.x;
  const int wave = tid >> 6;
  const int lane = tid & 63;
  __shared__ float buf[2][kH][64];
  const float* __restrict__ xb = x + (long)b * kT;
  float* __restrict__ outs_g = out + (long)b * kPerB + (long)(ng * 16) * kH;
  float* __restrict__ spks_g = outs_g + (long)kB * kPerB;
  if (wave == 0) {
    const int n = lane & 15;
    const float th = thresh[ng * 16 + n];
    float s = acc0[b * kN + ng * 16 + n];
    bool prev = false;
    for (int r = 0; r < kS + 1; ++r) {
      if (r < kS) {
        float* __restrict__ bk = &buf[r & 1][0][lane];
        const float* __restrict__ xr = xb + r * kH;
#pragma unroll
        for (int k = 0; k < kH; ++k) {
          const float xt = xr[k];
          const float u = s + xt;
          s = prev ? xt : u;
          prev = s > th;
          bk[k * 64] = s;
        }
      }
      __syncthreads();
    }
  } else {
    const int n = lane >> 2;
    const int hg = lane & 3;
    const float th = thresh[ng * 16 + n];
    for (int r = 0; r < kS + 1; ++r) {
      if (r > 0) {
        const int rr = r - 1;
        const float(*bk)[64] = buf[rr & 1];
        float* __restrict__ orow = outs_g + (long)rr * (kN * kH) + n * kH;
        float* __restrict__ srow = spks_g + (long)rr * (kN * kH) + n * kH;
#pragma unroll
        for (int i = 0; i < 8; ++i) {
          const int hh = hg * 4 + i * 16;
          v4f ovv, sv;
#pragma unroll
          for (int j = 0; j < 4; ++j) {
            const float v = bk[hh + j][n];
            const bool sp = v > th;
            ovv[j] = sp ? v : 0.0f;
            sv[j] = sp ? 1.0f : 0.0f;
          }
          *(v4f*)(orow + hh) = ovv;
          *(v4f*)(srow + hh) = sv;
        }
      }
      __syncthreads();
    }
  }
}

// ---------------------------------------------------------------------------
extern "C" void kernel_launch(void* const* d_in, const int* in_sizes, int n_in,
                              void* d_out, int out_size, void* d_ws, size_t ws_size,
                              hipStream_t stream) {
  const float* inputs = (const float*)d_in[0];    // [B,S,H] fp32
  const float* threshes = (const float*)d_in[1];  // [N] fp32
  const float* acc0 = (const float*)d_in[2];      // [B,N] fp32
  float* out = (float*)d_out;

  if (ws_size >= kWsZp + kWsS + kWsM) {
    uint2* zpackp = (uint2*)d_ws;
    float* ckpt_s = (float*)((char*)d_ws + kWsZp);
    u64* ckpt_m = (u64*)((char*)d_ws + kWsZp + kWsS);
    lif_zrun_kernel<<<kB * kS, kN, 0, stream>>>(inputs, threshes, zpackp);
    lif_stitch_kernel<<<kB, 128, 0, stream>>>(inputs, threshes, acc0, zpackp,
                                              ckpt_s, ckpt_m);
    lif_pass2_kernel<<<kB * kS, kN, 0, stream>>>(inputs, threshes, ckpt_s,
                                                 ckpt_m, out);
  } else if (ws_size >= kWsS + kWsM) {
    float* ckpt_s = (float*)d_ws;
    u64* ckpt_m = (u64*)((char*)d_ws + kWsS);
    lif_pass1_kernel<<<kB, kN, 0, stream>>>(inputs, threshes, acc0, ckpt_s,
                                            ckpt_m);
    lif_pass2_kernel<<<kB * kS, kN, 0, stream>>>(inputs, threshes, ckpt_s,
                                                 ckpt_m, out);
  } else {
    lif_fused_kernel<<<kB * 4, 128, 0, stream>>>(inputs, threshes, acc0, out);
  }
}

// Round 5
// 653.538 us; speedup vs baseline: 2.8441x; 1.1896x over previous
//
#include <hip/hip_runtime.h>

// LIF scan: B=16, S=256, H=128, N=64. T = S*H = 32768 sequential steps per
// (b,n) chain; 1024 chains. Bit-exactness with the fp32 sequential reference
// required -> add chain cannot be reassociated. Chain form (proven bit-exact):
//     s' = prev ? x : fl(s + x);  prev' = s' > th
//
// R12 = R11 resubmitted byte-identical: the R11 bench died with "container
// failed twice" (infra acquisition failure, no compile error, no counters).
// The R11 theory is untested; resubmitting unchanged keeps the A/B clean.
//
// R11 accounting insight: total - top_kernel has been ~255-265us EVERY round
// -> ~220us fixed harness overhead + pass2 ~40us + zrun ~15us. The only real
// lever is the stitch (514us = 4800 cyc/row).
//
// R10 stitch post-mortem: 8 per-group ballot+branch pairs (~50cy each) and
// blind-path LDS reads trapped behind `if(!done)` (VGPR=132 proves nothing
// hoisted -> ~24 serial dependent ds_reads ~2900cy on blind rows). Requiring
// ALL 64 lanes to coalesce in 31 steps makes blind rows common.
//
// R11: same producer/consumer LDS structure, same coalescence semantics
// (proven absmax=0), restructured consumer:
//  - ONE ballot per row (after step 31) instead of 8.
//  - 2-row software pipeline: prefetch next row's zp + q0..q15 during the
//    current row's 32-step chain (static buffer names, ping-pong via 2x
//    unrolled row calls -- no runtime-indexed arrays).
//  - blind path: 16 remaining quads loaded in two batches, each issued
//    before the 32-step chain that hides its latency.
// Per-row critical path ~350cy (coalesced) / ~1150cy (blind).

namespace {
constexpr int kB = 16;
constexpr int kS = 256;
constexpr int kH = 128;
constexpr int kN = 64;
constexpr int kT = kS * kH;                 // 32768
constexpr long kPerB = (long)kS * kN * kH;  // 2,097,152 per batch per tensor
// ws layout: zpack | ckpt_s | ckpt_m
constexpr size_t kWsZp = (size_t)kB * kS * kN * 8;                     // 2 MB
constexpr size_t kWsS = (size_t)kB * kS * kN * sizeof(float);          // 1 MB
constexpr size_t kWsM = (size_t)kB * kS * sizeof(unsigned long long);  // 32 KB
}

typedef float v4f __attribute__((ext_vector_type(4)));
typedef unsigned long long u64;

// Opaque VGPR zero: defeats uniform-scalarization so wave-uniform-looking
// loads use the vector path (vmcnt, in-order) instead of SMEM s_loads
// (lgkmcnt, unordered -> full drains). Proven effective in R6.
__device__ __forceinline__ int opaque_vgpr_zero() {
  int z;
  asm volatile("v_mov_b32 %0, 0" : "=v"(z));
  return z;
}

// ---------------------------------------------------------------------------
// K1z: z-run every (b,row) from the fresh state (prev=true -> step 0 gives
// s = x_0 exactly). Packed result: .x bits0..30 spike@step0..30, bit31 =
// exit prev (step 127); .y = bitcast(exit state). (unchanged from R10)
// ---------------------------------------------------------------------------
__global__ __launch_bounds__(64, 2) void lif_zrun_kernel(
    const float* __restrict__ x, const float* __restrict__ thresh,
    uint2* __restrict__ zpack) {
  const int wid = blockIdx.x;
  const int b = wid >> 8;
  const int srow = wid & 255;
  const int lane = threadIdx.x;

  const v4f* __restrict__ xr4 =
      (const v4f*)(x + (long)b * kT + srow * kH) + opaque_vgpr_zero();
  v4f xb[32];
#pragma unroll
  for (int i = 0; i < 32; ++i) xb[i] = xr4[i];  // 32 loads in flight

  const float th = thresh[lane];
  float s = 0.0f;
  bool prev = true;  // fresh start: step 0 takes s = x_0
  unsigned m = 0;

#pragma unroll
  for (int h = 0; h < kH; ++h) {
    const float xt = xb[h >> 2][h & 3];
    const float u = s + xt;
    s = prev ? xt : u;
    prev = s > th;
    if (h < 31) m |= (unsigned)prev << h;
    if (h == 127) m |= (unsigned)prev << 31;
  }
  uint2 zp;
  zp.x = m;
  zp.y = __float_as_uint(s);
  zpack[((long)b * kS + srow) * kN + lane] = zp;
}

// ---------------------------------------------------------------------------
// Consumer row body. ca/cb = current row quads 0..7 / 8..15 (in registers);
// zpc = current row zpack. Prefetches next row's (na, nb, zpn) during the
// 32-step chain. Semantics identical to R10's proven row logic.
// ---------------------------------------------------------------------------
__device__ __forceinline__ void stitch_row(
    const v4f* __restrict__ xq, const uint2* __restrict__ zq, const int jr,
    const int r, const float th, const int lane, float& s, bool& prev,
    v4f (&ca)[8], v4f (&cb)[8], const uint2 zpc, v4f (&na)[8], v4f (&nb)[8],
    uint2& zpn, float* __restrict__ cs, u64* __restrict__ cm) {
  // checkpoint: entering state
  cs[(long)r * kN] = s;
  {
    const u64 cmask = __ballot(prev);
    if (lane == 0) cm[r] = cmask;
  }
  const unsigned zm = zpc.x;
  const float ze = __uint_as_float(zpc.y);

  // prefetch next row (clamped within quarter; redundant at jr=63, unused)
  const int jn = jr + 1 < 64 ? jr + 1 : 63;
  zpn = zq[jn * 64 + lane];
#pragma unroll
  for (int i = 0; i < 8; ++i) na[i] = xq[jn * 32 + i];
#pragma unroll
  for (int i = 0; i < 8; ++i) nb[i] = xq[jn * 32 + 8 + i];

  float srun = s;
  bool prun = prev;
  bool live = !prev;  // prev_in=true: row IS the z-run, adopt z directly

  // steps 0..31: coalescence window is bits 0..30 of zm
#pragma unroll
  for (int g = 0; g < 8; ++g) {
#pragma unroll
    for (int j = 0; j < 4; ++j) {
      const int h = 4 * g + j;
      const float xt = ca[g][j];
      const float u = srun + xt;
      srun = prun ? xt : u;
      prun = srun > th;
      if (h < 31) live = live && !(prun && ((zm >> h) & 1u));
    }
  }

  if (__ballot(live) != 0) {
    // some lane uncoalesced: finish all 128 steps (per-lane select below
    // keeps coalesced lanes correct). Two pipelined load batches.
    v4f qc[8], qd[8];
#pragma unroll
    for (int i = 0; i < 8; ++i) qc[i] = xq[jr * 32 + 16 + i];
    // steps 32..63 from cb (already resident) hide qc latency
#pragma unroll
    for (int g = 0; g < 8; ++g) {
#pragma unroll
      for (int j = 0; j < 4; ++j) {
        const float xt = cb[g][j];
        const float u = srun + xt;
        srun = prun ? xt : u;
        prun = srun > th;
      }
    }
#pragma unroll
    for (int i = 0; i < 8; ++i) qd[i] = xq[jr * 32 + 24 + i];
    // steps 64..95 from qc hide qd latency
#pragma unroll
    for (int g = 0; g < 8; ++g) {
#pragma unroll
      for (int j = 0; j < 4; ++j) {
        const float xt = qc[g][j];
        const float u = srun + xt;
        srun = prun ? xt : u;
        prun = srun > th;
      }
    }
    // steps 96..127
#pragma unroll
    for (int g = 0; g < 8; ++g) {
#pragma unroll
      for (int j = 0; j < 4; ++j) {
        const float xt = qd[g][j];
        const float u = srun + xt;
        srun = prun ? xt : u;
        prun = srun > th;
      }
    }
  }
  // live == ran all 128 steps without coalescing (srun/prun are the truth);
  // else the z-run is authoritative from the coalescence step on.
  s = live ? srun : ze;
  prev = live ? prun : (bool)(zm >> 31);
}

// ---------------------------------------------------------------------------
// K2: stitch. One block per batch, 128 threads = {consumer wave, producer
// wave}. Producer double-buffers 64-row quarters of x (32KB) + zpack (32KB)
// into LDS; consumer carries true (s,prev) across 256 rows touching LDS
// only, 2-row software-pipelined. Emits the same checkpoints as before.
// ---------------------------------------------------------------------------
__global__ __launch_bounds__(128, 1) void lif_stitch_kernel(
    const float* __restrict__ x, const float* __restrict__ thresh,
    const float* __restrict__ acc0, const uint2* __restrict__ zpack,
    float* __restrict__ ckpt_s, u64* __restrict__ ckpt_m) {
  const int b = blockIdx.x;
  const int tid = threadIdx.x;
  const int wave = tid >> 6;
  const int lane = tid & 63;

  __shared__ v4f xsb[2][2048];  // 2 x 32KB: x quarter
  __shared__ v4f zsb[2][2048];  // 2 x 32KB: zpack quarter (type-punned uint2)

  if (wave == 1) {
    // ---- producer: stream quarters into LDS (unchanged from R10)
    const v4f* __restrict__ xg =
        (const v4f*)(x + (long)b * kT) + opaque_vgpr_zero();
    const v4f* __restrict__ zg =
        (const v4f*)(zpack + (long)b * kS * kN) + opaque_vgpr_zero();

#pragma unroll 1
    for (int q = -1; q < 3; ++q) {
      const int qq = q + 1;
      const int buf = qq & 1;
      const v4f* __restrict__ xsrc = xg + (long)qq * 2048;
      const v4f* __restrict__ zsrc = zg + (long)qq * 2048;
#pragma unroll 1
      for (int c = 0; c < 2; ++c) {
        v4f tx[16], tz[16];
#pragma unroll
        for (int i = 0; i < 16; ++i) tx[i] = xsrc[(c * 16 + i) * 64 + lane];
#pragma unroll
        for (int i = 0; i < 16; ++i) tz[i] = zsrc[(c * 16 + i) * 64 + lane];
#pragma unroll
        for (int i = 0; i < 16; ++i) xsb[buf][(c * 16 + i) * 64 + lane] = tx[i];
#pragma unroll
        for (int i = 0; i < 16; ++i) zsb[buf][(c * 16 + i) * 64 + lane] = tz[i];
      }
      __syncthreads();  // quarter qq ready / consumer done with buf (q>=0)
    }
    __syncthreads();  // match consumer's final barrier
  } else {
    // ---- consumer: the true chain, LDS-only, 2-row pipelined
    const float th = thresh[lane];
    float s = acc0[b * kN + lane];
    bool prev = false;

    float* __restrict__ cs = ckpt_s + (long)b * kS * kN + lane;
    u64* __restrict__ cm = ckpt_m + (long)b * kS;

    v4f qA[8], qB[8], qC[8], qD[8];  // E row: qA/qB; O row: qC/qD
    uint2 zpE, zpO;

    __syncthreads();  // quarter 0 staged
#pragma unroll 1
    for (int q = 0; q < 4; ++q) {
      const v4f* __restrict__ xq = xsb[q & 1];
      const uint2* __restrict__ zq = (const uint2*)zsb[q & 1];
      // prologue: load row 0 of this quarter (exposed once per quarter)
      zpE = zq[lane];
#pragma unroll
      for (int i = 0; i < 8; ++i) qA[i] = xq[i];
#pragma unroll
      for (int i = 0; i < 8; ++i) qB[i] = xq[8 + i];

#pragma unroll 1
      for (int k = 0; k < 32; ++k) {
        const int r0 = q * 64 + 2 * k;
        stitch_row(xq, zq, 2 * k, r0, th, lane, s, prev, qA, qB, zpE, qC, qD,
                   zpO, cs, cm);
        stitch_row(xq, zq, 2 * k + 1, r0 + 1, th, lane, s, prev, qC, qD, zpO,
                   qA, qB, zpE, cs, cm);
      }
      __syncthreads();  // hand buffer back to producer / next quarter ready
    }
  }
}

// ---------------------------------------------------------------------------
// K3: replay + dense coalesced write (byte-identical to R8/R9/R10 pass2,
// proven absmax = 0). One wave per (b,row); lane = n.
// ---------------------------------------------------------------------------
__global__ __launch_bounds__(64, 2) void lif_pass2_kernel(
    const float* __restrict__ x, const float* __restrict__ thresh,
    const float* __restrict__ ckpt_s, const u64* __restrict__ ckpt_m,
    float* __restrict__ out) {
  const int wid = blockIdx.x;
  const int b = wid >> 8;
  const int srow = wid & 255;
  const int lane = threadIdx.x;

  __shared__ float ov[kH / 2][kN + 1];  // 16.6 KB

  const v4f* __restrict__ xr4 =
      (const v4f*)(x + (long)b * kT + srow * kH) + opaque_vgpr_zero();

  v4f xb[32];
#pragma unroll
  for (int i = 0; i < 32; ++i) xb[i] = xr4[i];  // 32 loads in flight

  const float th = thresh[lane];
  float s = ckpt_s[((long)b * kS + srow) * kN + lane];
  bool prev = (ckpt_m[b * kS + srow] >> lane) & 1ULL;

  float* __restrict__ obase = out + (long)b * kPerB + (long)srow * (kN * kH);
  float* __restrict__ sbase = obase + (long)kB * kPerB;

#pragma unroll
  for (int half = 0; half < 2; ++half) {
#pragma unroll
    for (int hh = 0; hh < kH / 2; ++hh) {
      const int h = half * (kH / 2) + hh;
      const float xt = xb[h >> 2][h & 3];
      const float u = s + xt;
      s = prev ? xt : u;  // bit-identical replay
      prev = s > th;
      ov[hh][lane] = prev ? s : 0.0f;
    }
    const int q = lane & 15;
    const int nsub = lane >> 4;
    const int h0 = half * (kH / 2) + q * 4;
#pragma unroll
    for (int i = 0; i < 16; ++i) {
      const int n = i * 4 + nsub;
      v4f o, sp;
#pragma unroll
      for (int j = 0; j < 4; ++j) {
        const float v = ov[q * 4 + j][n];
        o[j] = v;
        sp[j] = v > 0.0f ? 1.0f : 0.0f;
      }
      *(v4f*)(obase + (long)n * kH + h0) = o;
      *(v4f*)(sbase + (long)n * kH + h0) = sp;
    }
  }
}

// ---------------------------------------------------------------------------
// Fallback A (ws in [1.03MB, 3.03MB)): R8 sequential pass1 + pass2.
// ---------------------------------------------------------------------------
__global__ __launch_bounds__(64, 1) void lif_pass1_kernel(
    const float* __restrict__ x, const float* __restrict__ thresh,
    const float* __restrict__ acc0, float* __restrict__ ckpt_s,
    u64* __restrict__ ckpt_m) {
  const int b = blockIdx.x;
  const int lane = threadIdx.x;
  const float th = thresh[lane];

  __shared__ v4f xs[2048];  // 32 KB: one quarter of this batch's x stream

  const v4f* __restrict__ xg =
      (const v4f*)(x + (long)b * kT) + opaque_vgpr_zero();

  float s = acc0[b * kN + lane];
  bool prev = false;

  float* __restrict__ cs = ckpt_s + (long)b * kS * kN + lane;
  u64* __restrict__ cm = ckpt_m + (long)b * kS;

  for (int q = 0; q < 4; ++q) {
    {
      const v4f* __restrict__ src = xg + (long)q * 2048 + lane;
      v4f tmp[32];
#pragma unroll
      for (int i = 0; i < 32; ++i) tmp[i] = src[i * 64];
#pragma unroll
      for (int i = 0; i < 32; ++i) xs[i * 64 + lane] = tmp[i];
    }
    for (int jrow = 0; jrow < 64; ++jrow) {
      const int r = q * 64 + jrow;
      cs[(long)r * kN] = s;
      {
        const u64 m = __ballot(prev);
        if (lane == 0) cm[r] = m;
      }
      const v4f* __restrict__ xr = &xs[jrow * 32];
#pragma unroll
      for (int k = 0; k < 32; ++k) {
        const v4f xv = xr[k];
#pragma unroll
        for (int j = 0; j < 4; ++j) {
          const float xt = xv[j];
          const float u = s + xt;
          s = prev ? xt : u;
          prev = s > th;
        }
      }
    }
  }
}

// ---------------------------------------------------------------------------
// Fallback B (tiny ws): R4's passing fused kernel (unchanged).
// ---------------------------------------------------------------------------
__global__ __launch_bounds__(128) void lif_fused_kernel(
    const float* __restrict__ x, const float* __restrict__ thresh,
    const float* __restrict__ acc0, float* __restrict__ out) {
  const int bid = blockIdx.x;
  const int b = bid >> 2;
  const int ng = bid & 3;
  const int tid = threadIdx.x;
  const int wave = tid >> 6;
  const int lane = tid & 63;
  __shared__ float buf[2][kH][64];
  const float* __restrict__ xb = x + (long)b * kT;
  float* __restrict__ outs_g = out + (long)b * kPerB + (long)(ng * 16) * kH;
  float* __restrict__ spks_g = outs_g + (long)kB * kPerB;
  if (wave == 0) {
    const int n = lane & 15;
    const float th = thresh[ng * 16 + n];
    float s = acc0[b * kN + ng * 16 + n];
    bool prev = false;
    for (int r = 0; r < kS + 1; ++r) {
      if (r < kS) {
        float* __restrict__ bk = &buf[r & 1][0][lane];
        const float* __restrict__ xr = xb + r * kH;
#pragma unroll
        for (int k = 0; k < kH; ++k) {
          const float xt = xr[k];
          const float u = s + xt;
          s = prev ? xt : u;
          prev = s > th;
          bk[k * 64] = s;
        }
      }
      __syncthreads();
    }
  } else {
    const int n = lane >> 2;
    const int hg = lane & 3;
    const float th = thresh[ng * 16 + n];
    for (int r = 0; r < kS + 1; ++r) {
      if (r > 0) {
        const int rr = r - 1;
        const float(*bk)[64] = buf[rr & 1];
        float* __restrict__ orow = outs_g + (long)rr * (kN * kH) + n * kH;
        float* __restrict__ srow = spks_g + (long)rr * (kN * kH) + n * kH;
#pragma unroll
        for (int i = 0; i < 8; ++i) {
          const int hh = hg * 4 + i * 16;
          v4f ovv, sv;
#pragma unroll
          for (int j = 0; j < 4; ++j) {
            const float v = bk[hh + j][n];
            const bool sp = v > th;
            ovv[j] = sp ? v : 0.0f;
            sv[j] = sp ? 1.0f : 0.0f;
          }
          *(v4f*)(orow + hh) = ovv;
          *(v4f*)(srow + hh) = sv;
        }
      }
      __syncthreads();
    }
  }
}

// ---------------------------------------------------------------------------
extern "C" void kernel_launch(void* const* d_in, const int* in_sizes, int n_in,
                              void* d_out, int out_size, void* d_ws, size_t ws_size,
                              hipStream_t stream) {
  const float* inputs = (const float*)d_in[0];    // [B,S,H] fp32
  const float* threshes = (const float*)d_in[1];  // [N] fp32
  const float* acc0 = (const float*)d_in[2];      // [B,N] fp32
  float* out = (float*)d_out;

  if (ws_size >= kWsZp + kWsS + kWsM) {
    uint2* zpackp = (uint2*)d_ws;
    float* ckpt_s = (float*)((char*)d_ws + kWsZp);
    u64* ckpt_m = (u64*)((char*)d_ws + kWsZp + kWsS);
    lif_zrun_kernel<<<kB * kS, kN, 0, stream>>>(inputs, threshes, zpackp);
    lif_stitch_kernel<<<kB, 128, 0, stream>>>(inputs, threshes, acc0, zpackp,
                                              ckpt_s, ckpt_m);
    lif_pass2_kernel<<<kB * kS, kN, 0, stream>>>(inputs, threshes, ckpt_s,
                                                 ckpt_m, out);
  } else if (ws_size >= kWsS + kWsM) {
    float* ckpt_s = (float*)d_ws;
    u64* ckpt_m = (u64*)((char*)d_ws + kWsS);
    lif_pass1_kernel<<<kB, kN, 0, stream>>>(inputs, threshes, acc0, ckpt_s,
                                            ckpt_m);
    lif_pass2_kernel<<<kB * kS, kN, 0, stream>>>(inputs, threshes, ckpt_s,
                                                 ckpt_m, out);
  } else {
    lif_fused_kernel<<<kB * 4, 128, 0, stream>>>(inputs, threshes, acc0, out);
  }
}